// Round 27
// baseline (444.598 us; speedup 1.0000x reference)
//
#include <hip/hip_runtime.h>

#define B_  2
#define S_  2048
#define D_  2048
#define H_  16
#define DH_ 128
#define L_  512
#define M_  (B_*S_)

typedef unsigned short u16;
typedef float f32x4 __attribute__((ext_vector_type(4)));
typedef short short8 __attribute__((ext_vector_type(8)));
typedef u16 u16x4 __attribute__((ext_vector_type(4)));
typedef u16 u16x8 __attribute__((ext_vector_type(8)));

__device__ inline float bf2f(u16 u) {
    union { unsigned int i; float f; } x; x.i = ((unsigned int)u) << 16; return x.f;
}
__device__ inline u16 f2bf(float f) {
    union { float f; unsigned int i; } x; x.f = f;
    unsigned int r = x.i + 0x7FFFu + ((x.i >> 16) & 1u);
    return (u16)(r >> 16);
}
__device__ inline f32x4 mfma16(short8 a, short8 b, f32x4 c) {
    return __builtin_amdgcn_mfma_f32_16x16x32_bf16(a, b, c, 0, 0, 0);
}

typedef const __attribute__((address_space(1))) unsigned int gu32;
typedef __attribute__((address_space(3))) unsigned int lu32;
__device__ inline void gload16(const u16* g, u16* l) {
    __builtin_amdgcn_global_load_lds((gu32*)g, (lu32*)l, 16, 0, 0);
}

template <typename T> __device__ inline void store1(T* p, float v);
template <> __device__ inline void store1<float>(float* p, float v) { *p = v; }
template <> __device__ inline void store1<u16>(u16* p, float v) { *p = f2bf(v); }

// ---------------------------------------------------------------------------
// MFMA GEMM: C = A @ B^T, A/B bf16, f32 accum.  BK=64 (r21-proven).
// NT = threads/block (template): 256 -> 4 waves, 128 -> 2 waves (r27: keeps
// 32 MFMA/wave/K-step density while doubling blocks/CU on grid-limited GEMMs).
// TRANS=false: C[M][N] row-major.  TRANS=true (u16): writes C^T[N][M].
// ---------------------------------------------------------------------------
template <typename TC, int BM, int BN, int WAVES_M, int WAVES_N, bool TRANS, int NT>
__global__ __launch_bounds__(NT) void mgemm(const u16* __restrict__ A,
                                            const u16* __restrict__ Bm,
                                            TC* __restrict__ C,
                                            int N, int K, int ldC) {
    constexpr int WM = BM / WAVES_M;
    constexpr int WN = BN / WAVES_N;
    constexpr int FM = WM / 16;
    constexpr int FN = WN / 16;
    constexpr int CA = (BM * 8) / NT;
    constexpr int CB = (BN * 8) / NT;

    const int tid = threadIdx.x;
    const int bn = blockIdx.x * BN, bm = blockIdx.y * BM;
    const int w = tid >> 6, l = tid & 63;
    const int wr = w / WAVES_N, wc = w % WAVES_N;
    const int g = l >> 4, ln16 = l & 15;

    __shared__ u16 A_lds[BM * 64];
    __shared__ u16 B_lds[BN * 64];

    f32x4 acc[FM][FN];
#pragma unroll
    for (int m = 0; m < FM; ++m)
#pragma unroll
        for (int n = 0; n < FN; ++n) acc[m][n] = {0.f, 0.f, 0.f, 0.f};

    for (int k0 = 0; k0 < K; k0 += 64) {
        __syncthreads();
#pragma unroll
        for (int i = 0; i < CA; ++i) {
            int ch = tid + i * NT;
            int row = ch % BM, ks = ch / BM;
            gload16(A + (size_t)(bm + row) * K + k0 + ks * 8, &A_lds[ch * 8]);
        }
#pragma unroll
        for (int i = 0; i < CB; ++i) {
            int ch = tid + i * NT;
            int row = ch % BN, ks = ch / BN;
            gload16(Bm + (size_t)(bn + row) * K + k0 + ks * 8, &B_lds[ch * 8]);
        }
        __syncthreads();

#pragma unroll
        for (int ko = 0; ko < 2; ++ko) {
            short8 af[FM], bf[FN];
#pragma unroll
            for (int m = 0; m < FM; ++m)
                af[m] = *reinterpret_cast<const short8*>(
                    &A_lds[((ko*4 + g) * BM + wr * WM + m * 16 + ln16) * 8]);
#pragma unroll
            for (int n = 0; n < FN; ++n)
                bf[n] = *reinterpret_cast<const short8*>(
                    &B_lds[((ko*4 + g) * BN + wc * WN + n * 16 + ln16) * 8]);
#pragma unroll
            for (int m = 0; m < FM; ++m)
#pragma unroll
                for (int n = 0; n < FN; ++n)
                    acc[m][n] = mfma16(af[m], bf[n], acc[m][n]);
        }
    }

    if constexpr (TRANS) {
#pragma unroll
        for (int m = 0; m < FM; ++m)
#pragma unroll
            for (int n = 0; n < FN; ++n) {
                u16x4 q4;
#pragma unroll
                for (int r = 0; r < 4; ++r) q4[r] = f2bf(acc[m][n][r]);
                *reinterpret_cast<u16x4*>(
                    (u16*)C + (size_t)(bn + wc*WN + n*16 + ln16) * ldC
                            + bm + wr*WM + m*16 + g*4) = q4;
            }
    } else {
#pragma unroll
        for (int m = 0; m < FM; ++m)
#pragma unroll
            for (int n = 0; n < FN; ++n)
#pragma unroll
                for (int r = 0; r < 4; ++r)
                    store1<TC>(&C[(size_t)(bm + wr*WM + m*16 + g*4 + r) * ldC + bn + wc*WN + n*16 + ln16],
                               acc[m][n][r]);
    }
}

// ---------------------------------------------------------------------------
// LayerNorm over L=512 per row, f32 out + bf16 out (fused cvt).
// ---------------------------------------------------------------------------
__global__ __launch_bounds__(256) void ln_fused(const float* __restrict__ pre,
                                                const float* __restrict__ w,
                                                const float* __restrict__ bias,
                                                float* __restrict__ out,
                                                u16* __restrict__ out_bf) {
    const int row = blockIdx.x;
    const int tid = threadIdx.x;
    __shared__ float red[256];
    const size_t base = (size_t)row * L_;
    float x0 = pre[base + tid];
    float x1 = pre[base + tid + 256];
    red[tid] = x0 + x1;
    __syncthreads();
    for (int o = 128; o; o >>= 1) { if (tid < o) red[tid] += red[tid + o]; __syncthreads(); }
    float mu = red[0] * (1.0f / L_);
    __syncthreads();
    float d0 = x0 - mu, d1 = x1 - mu;
    red[tid] = d0 * d0 + d1 * d1;
    __syncthreads();
    for (int o = 128; o; o >>= 1) { if (tid < o) red[tid] += red[tid + o]; __syncthreads(); }
    float rstd = rsqrtf(red[0] * (1.0f / L_) + 1e-5f);
    float y0 = d0 * rstd * w[tid]       + bias[tid];
    float y1 = d1 * rstd * w[tid + 256] + bias[tid + 256];
    out[base + tid]          = y0;
    out[base + tid + 256]    = y1;
    out_bf[base + tid]       = f2bf(y0);
    out_bf[base + tid + 256] = f2bf(y1);
}

// ---------------------------------------------------------------------------
// f32 -> bf16 convert (4 elems/thread)
// ---------------------------------------------------------------------------
__global__ __launch_bounds__(256) void cvt_bf16(const float* __restrict__ in,
                                                u16* __restrict__ out) {
    size_t i = ((size_t)blockIdx.x * 256 + threadIdx.x) * 4;
    f32x4 v = *reinterpret_cast<const f32x4*>(&in[i]);
    u16x4 o; o[0]=f2bf(v[0]); o[1]=f2bf(v[1]); o[2]=f2bf(v[2]); o[3]=f2bf(v[3]);
    *reinterpret_cast<u16x4*>(&out[i]) = o;
}

// ---------------------------------------------------------------------------
// flash_split (r26-proven): V DMA-staged from transposed global V^T[hd][S]
// with pre-swizzled source blocks; K DMA; 8 waves x 16 q-rows.
// grid (16 bx, 16 hh, 3 c) = 768 blocks (3/CU); qt2 permutation triple.
// ---------------------------------------------------------------------------
__global__ __launch_bounds__(512) void flash_split(const u16* __restrict__ qb,
                                                   const u16* __restrict__ kmat,
                                                   const u16* __restrict__ vt,
                                                   u16* __restrict__ opart,
                                                   float* __restrict__ ml) {
    const int c  = blockIdx.z;
    const int bx = blockIdx.x;
    int qt2;
    if (c == 0)      qt2 = bx;
    else if (c == 1) qt2 = (bx + 8) & 15;
    else             qt2 = (bx < 8) ? (14 - 2*bx) : (31 - 2*bx);
    const int hh = blockIdx.y;
    const int tid = threadIdx.x;
    const int w = tid >> 6, l = tid & 63;
    const int g = l >> 4, ln16 = l & 15;

    const int nt = 2*qt2 + 2;
    const int kt0   = (c * nt) / 3;
    const int ktend = ((c + 1) * nt) / 3;
    if (ktend <= kt0) {                   // empty chunk: mark LSE absent
        if (tid < 128) ml[(size_t)(c*16 + hh)*S_ + qt2*128 + tid] = -3e38f;
        return;
    }

    __shared__ u16 K_lds[8192];           // [ks 0..15][row 0..63][8]
    __shared__ char V_lds[16384];         // [dv 0..127][kv blk ^ (dv&7)][8]
    __shared__ char P_lds[16384];         // 8 waves x 2 KB
    char* P_my = P_lds + w * 2048;

    short8 qreg[4];
    {
        const u16* qbase = qb + (size_t)(qt2*128 + w*16 + ln16) * D_ + hh * DH_ + g*8;
#pragma unroll
        for (int kc = 0; kc < 4; ++kc)
            qreg[kc] = *reinterpret_cast<const short8*>(qbase + kc*32);
    }

    float m_run = -3e38f, l_run = 0.f;
    f32x4 acc[8];
#pragma unroll
    for (int cb = 0; cb < 8; ++cb) acc[cb] = {0,0,0,0};

    const int sq = qt2*128 + w*16 + ln16;
    const float scale = 0.08838834764831845f;

    for (int kt = kt0; kt < ktend; ++kt) {
        __syncthreads();
        // ---- K tile DMA (16 KB)
        const u16* ksrc = kmat + (size_t)kt * 64 * D_ + hh * DH_;
#pragma unroll
        for (int i = 0; i < 2; ++i) {
            int ch = tid + i * 512;
            int row = ch & 63, ks = ch >> 6;
            gload16(ksrc + (size_t)row * D_ + ks * 8, &K_lds[ch * 8]);
        }
        // ---- V tile DMA from V^T (pre-swizzled source blocks)
        const u16* vsrc = vt + (size_t)(hh * DH_) * S_ + kt * 64;
#pragma unroll
        for (int i = 0; i < 2; ++i) {
            int ch = tid + i * 512;
            int dv = ch >> 3, c16 = ch & 7;
            int srcblk = c16 ^ (dv & 7);
            gload16(vsrc + (size_t)dv * S_ + srcblk * 8, (u16*)V_lds + ch * 8);
        }
        __syncthreads();

        // ---- QK^T (swapped: A=K rows, B=Q rows), d=128 -> 16 MFMA
        f32x4 sacc[4];
#pragma unroll
        for (int a = 0; a < 4; ++a) sacc[a] = {0,0,0,0};
#pragma unroll
        for (int a = 0; a < 4; ++a) {
            const int row = a*16 + ln16;
#pragma unroll
            for (int kc = 0; kc < 4; ++kc) {
                short8 kf = *reinterpret_cast<const short8*>(&K_lds[((kc*4 + g)*64 + row) * 8]);
                sacc[a] = mfma16(kf, qreg[kc], sacc[a]);
            }
        }

        // ---- online softmax (lane owns q = ln16)
        float p[4][4];
        float tmax = -3e38f;
#pragma unroll
        for (int a = 0; a < 4; ++a)
#pragma unroll
            for (int r = 0; r < 4; ++r) {
                int t = kt*64 + a*16 + g*4 + r;
                float v = (t <= sq) ? sacc[a][r] * scale : -3e38f;
                p[a][r] = v;
                tmax = fmaxf(tmax, v);
            }
        tmax = fmaxf(tmax, __shfl_xor(tmax, 16, 64));
        tmax = fmaxf(tmax, __shfl_xor(tmax, 32, 64));
        float m_new = fmaxf(m_run, tmax);
        float fac = __expf(m_run - m_new);
        float rsum = 0.f;
#pragma unroll
        for (int a = 0; a < 4; ++a)
#pragma unroll
            for (int r = 0; r < 4; ++r) {
                float e = __expf(p[a][r] - m_new);
                p[a][r] = e;
                rsum += e;
            }
        rsum += __shfl_xor(rsum, 16, 64);
        rsum += __shfl_xor(rsum, 32, 64);
        l_run = l_run * fac + rsum;
        m_run = m_new;

        // ---- P -> wave-local LDS (bf16)
        {
            const int ps = (ln16 & 7) << 4;
#pragma unroll
            for (int a = 0; a < 4; ++a) {
                u16x4 quad;
#pragma unroll
                for (int r = 0; r < 4; ++r) quad[r] = f2bf(p[a][r]);
                *reinterpret_cast<u16x4*>(P_my + ((ln16*128 + a*32 + g*8) ^ ps)) = quad;
            }
        }
        // ---- rescale ctx
        float fr[4];
#pragma unroll
        for (int r = 0; r < 4; ++r) fr[r] = __shfl(fac, g*4 + r, 64);
#pragma unroll
        for (int cb = 0; cb < 8; ++cb)
#pragma unroll
            for (int r = 0; r < 4; ++r) acc[cb][r] *= fr[r];

        // ---- PV (swizzled b128 reads)
#pragma unroll
        for (int kc2 = 0; kc2 < 2; ++kc2) {
            short8 pf = *reinterpret_cast<const short8*>(
                P_my + ((ln16*128 + kc2*64 + g*16) ^ ((ln16 & 7) << 4)));
#pragma unroll
            for (int cb = 0; cb < 8; ++cb) {
                const int dv = cb*16 + ln16;
                short8 vf = *reinterpret_cast<const short8*>(
                    V_lds + ((dv*128 + kc2*64 + g*16) ^ ((dv & 7) << 4)));
                acc[cb] = mfma16(pf, vf, acc[cb]);
            }
        }
    }

    // ---- epilogue: normalized partial + LSE
    float inv = 1.0f / l_run;
    float lse = m_run + __logf(l_run);
    float ir[4];
#pragma unroll
    for (int r = 0; r < 4; ++r) ir[r] = __shfl(inv, g*4 + r, 64);
#pragma unroll
    for (int cb = 0; cb < 8; ++cb)
#pragma unroll
        for (int r = 0; r < 4; ++r) {
            int q = qt2*128 + w*16 + g*4 + r;
            opart[((size_t)(c*16 + hh)*S_ + q)*128 + cb*16 + ln16] = f2bf(acc[cb][r] * ir[r]);
        }
    if (g == 0) ml[(size_t)(c*16 + hh)*S_ + qt2*128 + w*16 + ln16] = lse;
}

// ---------------------------------------------------------------------------
// combine: 3-way LSE blend with empty-chunk guard.  grid 2048 x 256.
// ---------------------------------------------------------------------------
__global__ __launch_bounds__(256) void combine(const u16* __restrict__ opart,
                                               const float* __restrict__ ml,
                                               u16* __restrict__ ctx) {
    int t = blockIdx.x * 256 + threadIdx.x;
    int qh = t >> 4;
    int q = qh >> 4, hh = qh & 15;
    int dv0 = (t & 15) * 8;

    float ls[3], m = -3e38f;
#pragma unroll
    for (int c = 0; c < 3; ++c) {
        ls[c] = ml[(size_t)(c*16 + hh) * S_ + q];
        m = fmaxf(m, ls[c]);
    }
    float e[3], s = 0.f;
#pragma unroll
    for (int c = 0; c < 3; ++c) { e[c] = __expf(ls[c] - m); s += e[c]; }
    float is = 1.0f / s;

    float accv[8] = {};
#pragma unroll
    for (int c = 0; c < 3; ++c) {
        if (e[c] > 0.f) {
            u16x8 a = *reinterpret_cast<const u16x8*>(
                &opart[((size_t)(c*16 + hh)*S_ + q)*128 + dv0]);
#pragma unroll
            for (int j = 0; j < 8; ++j) accv[j] += e[c] * bf2f(a[j]);
        }
    }
    u16x8 o;
#pragma unroll
    for (int j = 0; j < 8; ++j) o[j] = f2bf(accv[j] * is);
    *reinterpret_cast<u16x8*>(&ctx[(size_t)q * D_ + hh * DH_ + dv0]) = o;
}

// ---------------------------------------------------------------------------
// r27 orchestration == r26 plan; q/out/k GEMMs use 128x64 2-wave (NT=128)
// tiles -> 1024 blocks = 4/CU at unchanged 32 MFMA/wave/K-step density.
// ---------------------------------------------------------------------------
extern "C" void kernel_launch(void* const* d_in, const int* in_sizes, int n_in,
                              void* d_out, int out_size, void* d_ws, size_t ws_size,
                              hipStream_t stream) {
    const float* x    = (const float*)d_in[0];
    const float* Wq   = (const float*)d_in[1];
    const float* Wdkv = (const float*)d_in[2];
    const float* Wuk  = (const float*)d_in[3];
    const float* Wuv  = (const float*)d_in[4];
    const float* Wo   = (const float*)d_in[5];
    const float* lnw  = (const float*)d_in[6];
    const float* lnb  = (const float*)d_in[7];

    float* out = (float*)d_out;
    float* ckv = out + (size_t)M_ * D_;               // (M,L) real output

    char* ws = (char*)d_ws;
    u16*   xb_bf   = (u16*)(ws);                      // S0 (16 MiB)
    u16*   kmat    = (u16*)(ws);                      //   reuse after xb dead
    u16*   qb_bf   = (u16*)(ws + (size_t)16777216);   // S1 full-M
    u16*   ctx_all = (u16*)(ws + (size_t)16777216);   //   ctx full-M (reuse)
    u16*   vt      = (u16*)(ws + (size_t)33554432);   // S2: V^T per batch
    u16*   wo_bf   = (u16*)(ws + (size_t)33554432);   //   reuse after flash(b1)
    u16*   ckv_bf  = (u16*)(ws + (size_t)41943040);   // S3 full-M (4 MiB)
    u16*   wuv_bf  = (u16*)(ws + (size_t)46137344);   // S4 (2 MiB)

    char*  ob0     = (char*)d_out;
    u16*   wslot   = (u16*)ob0;                       // phase-A weight slot
    float* ckvp    = (float*)(ob0 + 8388608);         // phase-A f32 scratch
    u16*   opart   = (u16*)d_out;                     // [0,24Mi) during flash
    float* ml      = (float*)(ob0 + 25165824);        // [24Mi,24.4Mi)

    dim3 blk(256);

    // ---- Phase A (batch-fused projections) ----
    cvt_bf16<<<dim3(8192), blk, 0, stream>>>(x, xb_bf);
    cvt_bf16<<<dim3(1024), blk, 0, stream>>>(Wdkv, wslot);
    mgemm<float,64,64,2,2,false,256><<<dim3(L_/64, M_/64), blk, 0, stream>>>(xb_bf, wslot, ckvp, L_, D_, L_);
    ln_fused<<<dim3(M_), blk, 0, stream>>>(ckvp, lnw, lnb, ckv, ckv_bf);
    cvt_bf16<<<dim3(4096), blk, 0, stream>>>(Wq, wslot);
    mgemm<u16,128,64,2,1,false,128><<<dim3(D_/64, M_/128), dim3(128), 0, stream>>>(xb_bf, wslot, qb_bf, D_, D_, D_);
    cvt_bf16<<<dim3(1024), blk, 0, stream>>>(Wuv, wuv_bf);
    cvt_bf16<<<dim3(1024), blk, 0, stream>>>(Wuk, wslot);
    mgemm<u16,128,64,2,1,false,128><<<dim3(D_/64, M_/128), dim3(128), 0, stream>>>(ckv_bf, wslot, kmat, D_, L_, D_);

    // ---- Per-batch attention ----
    for (int b = 0; b < B_; ++b) {
        const u16* qb_b    = qb_bf  + (size_t)b * S_ * D_;
        const u16* kmat_b  = kmat   + (size_t)b * S_ * D_;
        const u16* ckvbf_b = ckv_bf + (size_t)b * S_ * L_;
        u16*       ctx_b   = ctx_all + (size_t)b * S_ * D_;

        // v^T_b = (ckv_b @ Wuv^T)^T  -> vt [D][S]
        mgemm<u16,128,64,4,1,true,256><<<dim3(D_/64, S_/128), blk, 0, stream>>>(ckvbf_b, wuv_bf, vt, D_, L_, S_);

        // 3-way split flash + combine (ctx into dead qb_b half)
        flash_split<<<dim3(16, 16, 3), dim3(512), 0, stream>>>(
            qb_b, kmat_b, vt, opart, ml);
        combine<<<dim3(2048), blk, 0, stream>>>(opart, ml, ctx_b);
    }

    // ---- Merged output projection: out = ctx_all @ Wo^T (M=4096) ----
    cvt_bf16<<<dim3(4096), blk, 0, stream>>>(Wo, wo_bf);
    mgemm<float,128,64,2,1,false,128><<<dim3(D_/64, M_/128), dim3(128), 0, stream>>>(ctx_all, wo_bf, out, D_, D_, D_);
}

// Round 28
// 365.528 us; speedup vs baseline: 1.2163x; 1.2163x over previous
//
#include <hip/hip_runtime.h>

#define B_  2
#define S_  2048
#define D_  2048
#define H_  16
#define DH_ 128
#define L_  512
#define M_  (B_*S_)

typedef unsigned short u16;
typedef float f32x4 __attribute__((ext_vector_type(4)));
typedef short short8 __attribute__((ext_vector_type(8)));
typedef u16 u16x4 __attribute__((ext_vector_type(4)));
typedef u16 u16x8 __attribute__((ext_vector_type(8)));

__device__ inline float bf2f(u16 u) {
    union { unsigned int i; float f; } x; x.i = ((unsigned int)u) << 16; return x.f;
}
__device__ inline u16 f2bf(float f) {
    union { float f; unsigned int i; } x; x.f = f;
    unsigned int r = x.i + 0x7FFFu + ((x.i >> 16) & 1u);
    return (u16)(r >> 16);
}
__device__ inline f32x4 mfma16(short8 a, short8 b, f32x4 c) {
    return __builtin_amdgcn_mfma_f32_16x16x32_bf16(a, b, c, 0, 0, 0);
}

typedef const __attribute__((address_space(1))) unsigned int gu32;
typedef __attribute__((address_space(3))) unsigned int lu32;
__device__ inline void gload16(const u16* g, u16* l) {
    __builtin_amdgcn_global_load_lds((gu32*)g, (lu32*)l, 16, 0, 0);
}

template <typename T> __device__ inline void store1(T* p, float v);
template <> __device__ inline void store1<float>(float* p, float v) { *p = v; }
template <> __device__ inline void store1<u16>(u16* p, float v) { *p = f2bf(v); }

// ---------------------------------------------------------------------------
// MFMA GEMM: C = A @ B^T, A/B bf16, f32 accum.  BK=64 (r21-proven).
// TRANS=false: C[M][N] row-major, ld = ldC.
// TRANS=true (u16 only): writes C^T[N][M], ld = ldC (u16x4 per lane, 8B segs).
// r28: reverted to r26-proven configs (128x128 4-wave; r27's 2-wave lost
// intra-block latency hiding: MfmaUtil 16->11.5).
// ---------------------------------------------------------------------------
template <typename TC, int BM, int BN, int WAVES_M, int WAVES_N, bool TRANS>
__global__ __launch_bounds__(256) void mgemm(const u16* __restrict__ A,
                                             const u16* __restrict__ Bm,
                                             TC* __restrict__ C,
                                             int N, int K, int ldC) {
    constexpr int WM = BM / WAVES_M;
    constexpr int WN = BN / WAVES_N;
    constexpr int FM = WM / 16;
    constexpr int FN = WN / 16;
    constexpr int CA = (BM * 8) / 256;
    constexpr int CB = (BN * 8) / 256;

    const int tid = threadIdx.x;
    const int bn = blockIdx.x * BN, bm = blockIdx.y * BM;
    const int w = tid >> 6, l = tid & 63;
    const int wr = w / WAVES_N, wc = w % WAVES_N;
    const int g = l >> 4, ln16 = l & 15;

    __shared__ u16 A_lds[BM * 64];
    __shared__ u16 B_lds[BN * 64];

    f32x4 acc[FM][FN];
#pragma unroll
    for (int m = 0; m < FM; ++m)
#pragma unroll
        for (int n = 0; n < FN; ++n) acc[m][n] = {0.f, 0.f, 0.f, 0.f};

    for (int k0 = 0; k0 < K; k0 += 64) {
        __syncthreads();
#pragma unroll
        for (int i = 0; i < CA; ++i) {
            int ch = tid + i * 256;
            int row = ch % BM, ks = ch / BM;
            gload16(A + (size_t)(bm + row) * K + k0 + ks * 8, &A_lds[ch * 8]);
        }
#pragma unroll
        for (int i = 0; i < CB; ++i) {
            int ch = tid + i * 256;
            int row = ch % BN, ks = ch / BN;
            gload16(Bm + (size_t)(bn + row) * K + k0 + ks * 8, &B_lds[ch * 8]);
        }
        __syncthreads();

#pragma unroll
        for (int ko = 0; ko < 2; ++ko) {
            short8 af[FM], bf[FN];
#pragma unroll
            for (int m = 0; m < FM; ++m)
                af[m] = *reinterpret_cast<const short8*>(
                    &A_lds[((ko*4 + g) * BM + wr * WM + m * 16 + ln16) * 8]);
#pragma unroll
            for (int n = 0; n < FN; ++n)
                bf[n] = *reinterpret_cast<const short8*>(
                    &B_lds[((ko*4 + g) * BN + wc * WN + n * 16 + ln16) * 8]);
#pragma unroll
            for (int m = 0; m < FM; ++m)
#pragma unroll
                for (int n = 0; n < FN; ++n)
                    acc[m][n] = mfma16(af[m], bf[n], acc[m][n]);
        }
    }

    if constexpr (TRANS) {
        // C^T[col][row]: lane writes 4 consecutive rows (g*4+r) of its column
#pragma unroll
        for (int m = 0; m < FM; ++m)
#pragma unroll
            for (int n = 0; n < FN; ++n) {
                u16x4 q4;
#pragma unroll
                for (int r = 0; r < 4; ++r) q4[r] = f2bf(acc[m][n][r]);
                *reinterpret_cast<u16x4*>(
                    (u16*)C + (size_t)(bn + wc*WN + n*16 + ln16) * ldC
                            + bm + wr*WM + m*16 + g*4) = q4;
            }
    } else {
#pragma unroll
        for (int m = 0; m < FM; ++m)
#pragma unroll
            for (int n = 0; n < FN; ++n)
#pragma unroll
                for (int r = 0; r < 4; ++r)
                    store1<TC>(&C[(size_t)(bm + wr*WM + m*16 + g*4 + r) * ldC + bn + wc*WN + n*16 + ln16],
                               acc[m][n][r]);
    }
}

// ---------------------------------------------------------------------------
// LayerNorm over L=512 per row, f32 out + bf16 out (fused cvt).
// ---------------------------------------------------------------------------
__global__ __launch_bounds__(256) void ln_fused(const float* __restrict__ pre,
                                                const float* __restrict__ w,
                                                const float* __restrict__ bias,
                                                float* __restrict__ out,
                                                u16* __restrict__ out_bf) {
    const int row = blockIdx.x;
    const int tid = threadIdx.x;
    __shared__ float red[256];
    const size_t base = (size_t)row * L_;
    float x0 = pre[base + tid];
    float x1 = pre[base + tid + 256];
    red[tid] = x0 + x1;
    __syncthreads();
    for (int o = 128; o; o >>= 1) { if (tid < o) red[tid] += red[tid + o]; __syncthreads(); }
    float mu = red[0] * (1.0f / L_);
    __syncthreads();
    float d0 = x0 - mu, d1 = x1 - mu;
    red[tid] = d0 * d0 + d1 * d1;
    __syncthreads();
    for (int o = 128; o; o >>= 1) { if (tid < o) red[tid] += red[tid + o]; __syncthreads(); }
    float rstd = rsqrtf(red[0] * (1.0f / L_) + 1e-5f);
    float y0 = d0 * rstd * w[tid]       + bias[tid];
    float y1 = d1 * rstd * w[tid + 256] + bias[tid + 256];
    out[base + tid]          = y0;
    out[base + tid + 256]    = y1;
    out_bf[base + tid]       = f2bf(y0);
    out_bf[base + tid + 256] = f2bf(y1);
}

// ---------------------------------------------------------------------------
// f32 -> bf16 convert (4 elems/thread)
// ---------------------------------------------------------------------------
__global__ __launch_bounds__(256) void cvt_bf16(const float* __restrict__ in,
                                                u16* __restrict__ out) {
    size_t i = ((size_t)blockIdx.x * 256 + threadIdx.x) * 4;
    f32x4 v = *reinterpret_cast<const f32x4*>(&in[i]);
    u16x4 o; o[0]=f2bf(v[0]); o[1]=f2bf(v[1]); o[2]=f2bf(v[2]); o[3]=f2bf(v[3]);
    *reinterpret_cast<u16x4*>(&out[i]) = o;
}

// ---------------------------------------------------------------------------
// flash_split (r26-proven): V DMA-staged from transposed global V^T[hd][S]
// with pre-swizzled source blocks; K DMA; 8 waves x 16 q-rows.
// grid (16 bx, 16 hh, 3 c) = 768 blocks (3/CU); qt2 permutation triple.
// ---------------------------------------------------------------------------
__global__ __launch_bounds__(512) void flash_split(const u16* __restrict__ qb,
                                                   const u16* __restrict__ kmat,
                                                   const u16* __restrict__ vt,
                                                   u16* __restrict__ opart,
                                                   float* __restrict__ ml) {
    const int c  = blockIdx.z;
    const int bx = blockIdx.x;
    int qt2;
    if (c == 0)      qt2 = bx;
    else if (c == 1) qt2 = (bx + 8) & 15;
    else             qt2 = (bx < 8) ? (14 - 2*bx) : (31 - 2*bx);
    const int hh = blockIdx.y;
    const int tid = threadIdx.x;
    const int w = tid >> 6, l = tid & 63;
    const int g = l >> 4, ln16 = l & 15;

    const int nt = 2*qt2 + 2;
    const int kt0   = (c * nt) / 3;
    const int ktend = ((c + 1) * nt) / 3;
    if (ktend <= kt0) {                   // empty chunk: mark LSE absent
        if (tid < 128) ml[(size_t)(c*16 + hh)*S_ + qt2*128 + tid] = -3e38f;
        return;
    }

    __shared__ u16 K_lds[8192];           // [ks 0..15][row 0..63][8]
    __shared__ char V_lds[16384];         // [dv 0..127][kv blk ^ (dv&7)][8]
    __shared__ char P_lds[16384];         // 8 waves x 2 KB
    char* P_my = P_lds + w * 2048;

    short8 qreg[4];
    {
        const u16* qbase = qb + (size_t)(qt2*128 + w*16 + ln16) * D_ + hh * DH_ + g*8;
#pragma unroll
        for (int kc = 0; kc < 4; ++kc)
            qreg[kc] = *reinterpret_cast<const short8*>(qbase + kc*32);
    }

    float m_run = -3e38f, l_run = 0.f;
    f32x4 acc[8];
#pragma unroll
    for (int cb = 0; cb < 8; ++cb) acc[cb] = {0,0,0,0};

    const int sq = qt2*128 + w*16 + ln16;
    const float scale = 0.08838834764831845f;

    for (int kt = kt0; kt < ktend; ++kt) {
        __syncthreads();
        // ---- K tile DMA (16 KB)
        const u16* ksrc = kmat + (size_t)kt * 64 * D_ + hh * DH_;
#pragma unroll
        for (int i = 0; i < 2; ++i) {
            int ch = tid + i * 512;
            int row = ch & 63, ks = ch >> 6;
            gload16(ksrc + (size_t)row * D_ + ks * 8, &K_lds[ch * 8]);
        }
        // ---- V tile DMA from V^T (pre-swizzled source blocks)
        const u16* vsrc = vt + (size_t)(hh * DH_) * S_ + kt * 64;
#pragma unroll
        for (int i = 0; i < 2; ++i) {
            int ch = tid + i * 512;
            int dv = ch >> 3, c16 = ch & 7;
            int srcblk = c16 ^ (dv & 7);
            gload16(vsrc + (size_t)dv * S_ + srcblk * 8, (u16*)V_lds + ch * 8);
        }
        __syncthreads();

        // ---- QK^T (swapped: A=K rows, B=Q rows), d=128 -> 16 MFMA
        f32x4 sacc[4];
#pragma unroll
        for (int a = 0; a < 4; ++a) sacc[a] = {0,0,0,0};
#pragma unroll
        for (int a = 0; a < 4; ++a) {
            const int row = a*16 + ln16;
#pragma unroll
            for (int kc = 0; kc < 4; ++kc) {
                short8 kf = *reinterpret_cast<const short8*>(&K_lds[((kc*4 + g)*64 + row) * 8]);
                sacc[a] = mfma16(kf, qreg[kc], sacc[a]);
            }
        }

        // ---- online softmax (lane owns q = ln16)
        float p[4][4];
        float tmax = -3e38f;
#pragma unroll
        for (int a = 0; a < 4; ++a)
#pragma unroll
            for (int r = 0; r < 4; ++r) {
                int t = kt*64 + a*16 + g*4 + r;
                float v = (t <= sq) ? sacc[a][r] * scale : -3e38f;
                p[a][r] = v;
                tmax = fmaxf(tmax, v);
            }
        tmax = fmaxf(tmax, __shfl_xor(tmax, 16, 64));
        tmax = fmaxf(tmax, __shfl_xor(tmax, 32, 64));
        float m_new = fmaxf(m_run, tmax);
        float fac = __expf(m_run - m_new);
        float rsum = 0.f;
#pragma unroll
        for (int a = 0; a < 4; ++a)
#pragma unroll
            for (int r = 0; r < 4; ++r) {
                float e = __expf(p[a][r] - m_new);
                p[a][r] = e;
                rsum += e;
            }
        rsum += __shfl_xor(rsum, 16, 64);
        rsum += __shfl_xor(rsum, 32, 64);
        l_run = l_run * fac + rsum;
        m_run = m_new;

        // ---- P -> wave-local LDS (bf16)
        {
            const int ps = (ln16 & 7) << 4;
#pragma unroll
            for (int a = 0; a < 4; ++a) {
                u16x4 quad;
#pragma unroll
                for (int r = 0; r < 4; ++r) quad[r] = f2bf(p[a][r]);
                *reinterpret_cast<u16x4*>(P_my + ((ln16*128 + a*32 + g*8) ^ ps)) = quad;
            }
        }
        // ---- rescale ctx
        float fr[4];
#pragma unroll
        for (int r = 0; r < 4; ++r) fr[r] = __shfl(fac, g*4 + r, 64);
#pragma unroll
        for (int cb = 0; cb < 8; ++cb)
#pragma unroll
            for (int r = 0; r < 4; ++r) acc[cb][r] *= fr[r];

        // ---- PV (swizzled b128 reads)
#pragma unroll
        for (int kc2 = 0; kc2 < 2; ++kc2) {
            short8 pf = *reinterpret_cast<const short8*>(
                P_my + ((ln16*128 + kc2*64 + g*16) ^ ((ln16 & 7) << 4)));
#pragma unroll
            for (int cb = 0; cb < 8; ++cb) {
                const int dv = cb*16 + ln16;
                short8 vf = *reinterpret_cast<const short8*>(
                    V_lds + ((dv*128 + kc2*64 + g*16) ^ ((dv & 7) << 4)));
                acc[cb] = mfma16(pf, vf, acc[cb]);
            }
        }
    }

    // ---- epilogue: normalized partial + LSE
    float inv = 1.0f / l_run;
    float lse = m_run + __logf(l_run);
    float ir[4];
#pragma unroll
    for (int r = 0; r < 4; ++r) ir[r] = __shfl(inv, g*4 + r, 64);
#pragma unroll
    for (int cb = 0; cb < 8; ++cb)
#pragma unroll
        for (int r = 0; r < 4; ++r) {
            int q = qt2*128 + w*16 + g*4 + r;
            opart[((size_t)(c*16 + hh)*S_ + q)*128 + cb*16 + ln16] = f2bf(acc[cb][r] * ir[r]);
        }
    if (g == 0) ml[(size_t)(c*16 + hh)*S_ + qt2*128 + w*16 + ln16] = lse;
}

// ---------------------------------------------------------------------------
// combine: 3-way LSE blend with empty-chunk guard.  grid 2048 x 256.
// ---------------------------------------------------------------------------
__global__ __launch_bounds__(256) void combine(const u16* __restrict__ opart,
                                               const float* __restrict__ ml,
                                               u16* __restrict__ ctx) {
    int t = blockIdx.x * 256 + threadIdx.x;
    int qh = t >> 4;
    int q = qh >> 4, hh = qh & 15;
    int dv0 = (t & 15) * 8;

    float ls[3], m = -3e38f;
#pragma unroll
    for (int c = 0; c < 3; ++c) {
        ls[c] = ml[(size_t)(c*16 + hh) * S_ + q];
        m = fmaxf(m, ls[c]);
    }
    float e[3], s = 0.f;
#pragma unroll
    for (int c = 0; c < 3; ++c) { e[c] = __expf(ls[c] - m); s += e[c]; }
    float is = 1.0f / s;

    float accv[8] = {};
#pragma unroll
    for (int c = 0; c < 3; ++c) {
        if (e[c] > 0.f) {
            u16x8 a = *reinterpret_cast<const u16x8*>(
                &opart[((size_t)(c*16 + hh)*S_ + q)*128 + dv0]);
#pragma unroll
            for (int j = 0; j < 8; ++j) accv[j] += e[c] * bf2f(a[j]);
        }
    }
    u16x8 o;
#pragma unroll
    for (int j = 0; j < 8; ++j) o[j] = f2bf(accv[j] * is);
    *reinterpret_cast<u16x8*>(&ctx[(size_t)q * D_ + hh * DH_ + dv0]) = o;
}

// ---------------------------------------------------------------------------
// r28 orchestration == r26 (proven 366 us best):
// ws: S0 [0,16Mi): xb_bf -> kmat full-M
//     S1 [16Mi,32Mi): qb_bf full-M -> ctx full-M
//     S2 [32Mi,40Mi): vt (V^T [D][S] per batch) -> wo_bf after flash(b1)
//     S3 [40Mi,44Mi): ckv_bf  S4 [44Mi,46Mi): wuv_bf
// d_out: [0,24Mi) opart; [24Mi,24.4Mi) ml; final out [0,32Mi); ckv tail.
// ---------------------------------------------------------------------------
extern "C" void kernel_launch(void* const* d_in, const int* in_sizes, int n_in,
                              void* d_out, int out_size, void* d_ws, size_t ws_size,
                              hipStream_t stream) {
    const float* x    = (const float*)d_in[0];
    const float* Wq   = (const float*)d_in[1];
    const float* Wdkv = (const float*)d_in[2];
    const float* Wuk  = (const float*)d_in[3];
    const float* Wuv  = (const float*)d_in[4];
    const float* Wo   = (const float*)d_in[5];
    const float* lnw  = (const float*)d_in[6];
    const float* lnb  = (const float*)d_in[7];

    float* out = (float*)d_out;
    float* ckv = out + (size_t)M_ * D_;               // (M,L) real output

    char* ws = (char*)d_ws;
    u16*   xb_bf   = (u16*)(ws);                      // S0 (16 MiB)
    u16*   kmat    = (u16*)(ws);                      //   reuse after xb dead
    u16*   qb_bf   = (u16*)(ws + (size_t)16777216);   // S1 full-M
    u16*   ctx_all = (u16*)(ws + (size_t)16777216);   //   ctx full-M (reuse)
    u16*   vt      = (u16*)(ws + (size_t)33554432);   // S2: V^T per batch
    u16*   wo_bf   = (u16*)(ws + (size_t)33554432);   //   reuse after flash(b1)
    u16*   ckv_bf  = (u16*)(ws + (size_t)41943040);   // S3 full-M (4 MiB)
    u16*   wuv_bf  = (u16*)(ws + (size_t)46137344);   // S4 (2 MiB)

    char*  ob0     = (char*)d_out;
    u16*   wslot   = (u16*)ob0;                       // phase-A weight slot
    float* ckvp    = (float*)(ob0 + 8388608);         // phase-A f32 scratch
    u16*   opart   = (u16*)d_out;                     // [0,24Mi) during flash
    float* ml      = (float*)(ob0 + 25165824);        // [24Mi,24.4Mi)

    dim3 blk(256);

    // ---- Phase A (batch-fused projections) ----
    cvt_bf16<<<dim3(8192), blk, 0, stream>>>(x, xb_bf);
    cvt_bf16<<<dim3(1024), blk, 0, stream>>>(Wdkv, wslot);
    mgemm<float,64,64,2,2,false><<<dim3(L_/64, M_/64), blk, 0, stream>>>(xb_bf, wslot, ckvp, L_, D_, L_);
    ln_fused<<<dim3(M_), blk, 0, stream>>>(ckvp, lnw, lnb, ckv, ckv_bf);
    cvt_bf16<<<dim3(4096), blk, 0, stream>>>(Wq, wslot);
    mgemm<u16,128,128,2,2,false><<<dim3(D_/128, M_/128), blk, 0, stream>>>(xb_bf, wslot, qb_bf, D_, D_, D_);
    cvt_bf16<<<dim3(1024), blk, 0, stream>>>(Wuv, wuv_bf);
    cvt_bf16<<<dim3(1024), blk, 0, stream>>>(Wuk, wslot);
    mgemm<u16,128,128,2,2,false><<<dim3(D_/128, M_/128), blk, 0, stream>>>(ckv_bf, wslot, kmat, D_, L_, D_);

    // ---- Per-batch attention ----
    for (int b = 0; b < B_; ++b) {
        const u16* qb_b    = qb_bf  + (size_t)b * S_ * D_;
        const u16* kmat_b  = kmat   + (size_t)b * S_ * D_;
        const u16* ckvbf_b = ckv_bf + (size_t)b * S_ * L_;
        u16*       ctx_b   = ctx_all + (size_t)b * S_ * D_;

        // v^T_b = (ckv_b @ Wuv^T)^T  -> vt [D][S]
        mgemm<u16,128,64,4,1,true><<<dim3(D_/64, S_/128), blk, 0, stream>>>(ckvbf_b, wuv_bf, vt, D_, L_, S_);

        // 3-way split flash + combine (ctx into dead qb_b half)
        flash_split<<<dim3(16, 16, 3), dim3(512), 0, stream>>>(
            qb_b, kmat_b, vt, opart, ml);
        combine<<<dim3(2048), blk, 0, stream>>>(opart, ml, ctx_b);
    }

    // ---- Merged output projection: out = ctx_all @ Wo^T (M=4096) ----
    cvt_bf16<<<dim3(4096), blk, 0, stream>>>(Wo, wo_bf);
    mgemm<float,128,128,2,2,false><<<dim3(D_/128, M_/128), blk, 0, stream>>>(ctx_all, wo_bf, out, D_, D_, D_);
}

// Round 29
// 356.144 us; speedup vs baseline: 1.2484x; 1.0264x over previous
//
#include <hip/hip_runtime.h>

#define B_  2
#define S_  2048
#define D_  2048
#define H_  16
#define DH_ 128
#define L_  512
#define M_  (B_*S_)

typedef unsigned short u16;
typedef float f32x4 __attribute__((ext_vector_type(4)));
typedef short short8 __attribute__((ext_vector_type(8)));
typedef u16 u16x4 __attribute__((ext_vector_type(4)));
typedef u16 u16x8 __attribute__((ext_vector_type(8)));

__device__ inline float bf2f(u16 u) {
    union { unsigned int i; float f; } x; x.i = ((unsigned int)u) << 16; return x.f;
}
__device__ inline u16 f2bf(float f) {
    union { float f; unsigned int i; } x; x.f = f;
    unsigned int r = x.i + 0x7FFFu + ((x.i >> 16) & 1u);
    return (u16)(r >> 16);
}
__device__ inline f32x4 mfma16(short8 a, short8 b, f32x4 c) {
    return __builtin_amdgcn_mfma_f32_16x16x32_bf16(a, b, c, 0, 0, 0);
}

typedef const __attribute__((address_space(1))) unsigned int gu32;
typedef __attribute__((address_space(3))) unsigned int lu32;
__device__ inline void gload16(const u16* g, u16* l) {
    __builtin_amdgcn_global_load_lds((gu32*)g, (lu32*)l, 16, 0, 0);
}

template <typename T> __device__ inline void store1(T* p, float v);
template <> __device__ inline void store1<float>(float* p, float v) { *p = v; }
template <> __device__ inline void store1<u16>(u16* p, float v) { *p = f2bf(v); }

// ---------------------------------------------------------------------------
// MFMA GEMM: C = A @ B^T, A/B bf16, f32 accum.  BK=64, 128x128-class tiles,
// 4 waves (r21/r26-proven).  r29: XCD-chunked block swizzle (T1) — linear
// block id l -> (l&7)*(nwg/8) + l/8 so each XCD gets a contiguous grid chunk
// (B panel becomes L2-resident per XCD; FETCH was 2.9x ideal).
// Requires gridDim.x*gridDim.y % 8 == 0 (all our grids satisfy this).
// TRANS=false: C[M][N] row-major.  TRANS=true (u16): writes C^T[N][M].
// ---------------------------------------------------------------------------
template <typename TC, int BM, int BN, int WAVES_M, int WAVES_N, bool TRANS>
__global__ __launch_bounds__(256) void mgemm(const u16* __restrict__ A,
                                             const u16* __restrict__ Bm,
                                             TC* __restrict__ C,
                                             int N, int K, int ldC) {
    constexpr int WM = BM / WAVES_M;
    constexpr int WN = BN / WAVES_N;
    constexpr int FM = WM / 16;
    constexpr int FN = WN / 16;
    constexpr int CA = (BM * 8) / 256;
    constexpr int CB = (BN * 8) / 256;

    const int tid = threadIdx.x;

    // ---- XCD-chunked bijective swizzle (nwg % 8 == 0)
    const int gx = gridDim.x;
    const int nwg = gx * gridDim.y;
    const int lin = blockIdx.y * gx + blockIdx.x;
    const int cpx = nwg >> 3;                       // chunk per XCD
    const int swz = (lin & 7) * cpx + (lin >> 3);
    const int bxs = swz % gx, bys = swz / gx;

    const int bn = bxs * BN, bm = bys * BM;
    const int w = tid >> 6, l = tid & 63;
    const int wr = w / WAVES_N, wc = w % WAVES_N;
    const int g = l >> 4, ln16 = l & 15;

    __shared__ u16 A_lds[BM * 64];
    __shared__ u16 B_lds[BN * 64];

    f32x4 acc[FM][FN];
#pragma unroll
    for (int m = 0; m < FM; ++m)
#pragma unroll
        for (int n = 0; n < FN; ++n) acc[m][n] = {0.f, 0.f, 0.f, 0.f};

    for (int k0 = 0; k0 < K; k0 += 64) {
        __syncthreads();
#pragma unroll
        for (int i = 0; i < CA; ++i) {
            int ch = tid + i * 256;
            int row = ch % BM, ks = ch / BM;
            gload16(A + (size_t)(bm + row) * K + k0 + ks * 8, &A_lds[ch * 8]);
        }
#pragma unroll
        for (int i = 0; i < CB; ++i) {
            int ch = tid + i * 256;
            int row = ch % BN, ks = ch / BN;
            gload16(Bm + (size_t)(bn + row) * K + k0 + ks * 8, &B_lds[ch * 8]);
        }
        __syncthreads();

#pragma unroll
        for (int ko = 0; ko < 2; ++ko) {
            short8 af[FM], bf[FN];
#pragma unroll
            for (int m = 0; m < FM; ++m)
                af[m] = *reinterpret_cast<const short8*>(
                    &A_lds[((ko*4 + g) * BM + wr * WM + m * 16 + ln16) * 8]);
#pragma unroll
            for (int n = 0; n < FN; ++n)
                bf[n] = *reinterpret_cast<const short8*>(
                    &B_lds[((ko*4 + g) * BN + wc * WN + n * 16 + ln16) * 8]);
#pragma unroll
            for (int m = 0; m < FM; ++m)
#pragma unroll
                for (int n = 0; n < FN; ++n)
                    acc[m][n] = mfma16(af[m], bf[n], acc[m][n]);
        }
    }

    if constexpr (TRANS) {
#pragma unroll
        for (int m = 0; m < FM; ++m)
#pragma unroll
            for (int n = 0; n < FN; ++n) {
                u16x4 q4;
#pragma unroll
                for (int r = 0; r < 4; ++r) q4[r] = f2bf(acc[m][n][r]);
                *reinterpret_cast<u16x4*>(
                    (u16*)C + (size_t)(bn + wc*WN + n*16 + ln16) * ldC
                            + bm + wr*WM + m*16 + g*4) = q4;
            }
    } else {
#pragma unroll
        for (int m = 0; m < FM; ++m)
#pragma unroll
            for (int n = 0; n < FN; ++n)
#pragma unroll
                for (int r = 0; r < 4; ++r)
                    store1<TC>(&C[(size_t)(bm + wr*WM + m*16 + g*4 + r) * ldC + bn + wc*WN + n*16 + ln16],
                               acc[m][n][r]);
    }
}

// ---------------------------------------------------------------------------
// LayerNorm over L=512 per row, f32 out + bf16 out (fused cvt).
// ---------------------------------------------------------------------------
__global__ __launch_bounds__(256) void ln_fused(const float* __restrict__ pre,
                                                const float* __restrict__ w,
                                                const float* __restrict__ bias,
                                                float* __restrict__ out,
                                                u16* __restrict__ out_bf) {
    const int row = blockIdx.x;
    const int tid = threadIdx.x;
    __shared__ float red[256];
    const size_t base = (size_t)row * L_;
    float x0 = pre[base + tid];
    float x1 = pre[base + tid + 256];
    red[tid] = x0 + x1;
    __syncthreads();
    for (int o = 128; o; o >>= 1) { if (tid < o) red[tid] += red[tid + o]; __syncthreads(); }
    float mu = red[0] * (1.0f / L_);
    __syncthreads();
    float d0 = x0 - mu, d1 = x1 - mu;
    red[tid] = d0 * d0 + d1 * d1;
    __syncthreads();
    for (int o = 128; o; o >>= 1) { if (tid < o) red[tid] += red[tid + o]; __syncthreads(); }
    float rstd = rsqrtf(red[0] * (1.0f / L_) + 1e-5f);
    float y0 = d0 * rstd * w[tid]       + bias[tid];
    float y1 = d1 * rstd * w[tid + 256] + bias[tid + 256];
    out[base + tid]          = y0;
    out[base + tid + 256]    = y1;
    out_bf[base + tid]       = f2bf(y0);
    out_bf[base + tid + 256] = f2bf(y1);
}

// ---------------------------------------------------------------------------
// f32 -> bf16 convert (4 elems/thread)
// ---------------------------------------------------------------------------
__global__ __launch_bounds__(256) void cvt_bf16(const float* __restrict__ in,
                                                u16* __restrict__ out) {
    size_t i = ((size_t)blockIdx.x * 256 + threadIdx.x) * 4;
    f32x4 v = *reinterpret_cast<const f32x4*>(&in[i]);
    u16x4 o; o[0]=f2bf(v[0]); o[1]=f2bf(v[1]); o[2]=f2bf(v[2]); o[3]=f2bf(v[3]);
    *reinterpret_cast<u16x4*>(&out[i]) = o;
}

// ---------------------------------------------------------------------------
// flash_split (r26-proven): V DMA-staged from transposed global V^T[hd][S]
// with pre-swizzled source blocks; K DMA; 8 waves x 16 q-rows.
// grid (16 bx, 16 hh, 3 c) = 768 blocks (3/CU); qt2 permutation triple.
// ---------------------------------------------------------------------------
__global__ __launch_bounds__(512) void flash_split(const u16* __restrict__ qb,
                                                   const u16* __restrict__ kmat,
                                                   const u16* __restrict__ vt,
                                                   u16* __restrict__ opart,
                                                   float* __restrict__ ml) {
    const int c  = blockIdx.z;
    const int bx = blockIdx.x;
    int qt2;
    if (c == 0)      qt2 = bx;
    else if (c == 1) qt2 = (bx + 8) & 15;
    else             qt2 = (bx < 8) ? (14 - 2*bx) : (31 - 2*bx);
    const int hh = blockIdx.y;
    const int tid = threadIdx.x;
    const int w = tid >> 6, l = tid & 63;
    const int g = l >> 4, ln16 = l & 15;

    const int nt = 2*qt2 + 2;
    const int kt0   = (c * nt) / 3;
    const int ktend = ((c + 1) * nt) / 3;
    if (ktend <= kt0) {                   // empty chunk: mark LSE absent
        if (tid < 128) ml[(size_t)(c*16 + hh)*S_ + qt2*128 + tid] = -3e38f;
        return;
    }

    __shared__ u16 K_lds[8192];           // [ks 0..15][row 0..63][8]
    __shared__ char V_lds[16384];         // [dv 0..127][kv blk ^ (dv&7)][8]
    __shared__ char P_lds[16384];         // 8 waves x 2 KB
    char* P_my = P_lds + w * 2048;

    short8 qreg[4];
    {
        const u16* qbase = qb + (size_t)(qt2*128 + w*16 + ln16) * D_ + hh * DH_ + g*8;
#pragma unroll
        for (int kc = 0; kc < 4; ++kc)
            qreg[kc] = *reinterpret_cast<const short8*>(qbase + kc*32);
    }

    float m_run = -3e38f, l_run = 0.f;
    f32x4 acc[8];
#pragma unroll
    for (int cb = 0; cb < 8; ++cb) acc[cb] = {0,0,0,0};

    const int sq = qt2*128 + w*16 + ln16;
    const float scale = 0.08838834764831845f;

    for (int kt = kt0; kt < ktend; ++kt) {
        __syncthreads();
        // ---- K tile DMA (16 KB)
        const u16* ksrc = kmat + (size_t)kt * 64 * D_ + hh * DH_;
#pragma unroll
        for (int i = 0; i < 2; ++i) {
            int ch = tid + i * 512;
            int row = ch & 63, ks = ch >> 6;
            gload16(ksrc + (size_t)row * D_ + ks * 8, &K_lds[ch * 8]);
        }
        // ---- V tile DMA from V^T (pre-swizzled source blocks)
        const u16* vsrc = vt + (size_t)(hh * DH_) * S_ + kt * 64;
#pragma unroll
        for (int i = 0; i < 2; ++i) {
            int ch = tid + i * 512;
            int dv = ch >> 3, c16 = ch & 7;
            int srcblk = c16 ^ (dv & 7);
            gload16(vsrc + (size_t)dv * S_ + srcblk * 8, (u16*)V_lds + ch * 8);
        }
        __syncthreads();

        // ---- QK^T (swapped: A=K rows, B=Q rows), d=128 -> 16 MFMA
        f32x4 sacc[4];
#pragma unroll
        for (int a = 0; a < 4; ++a) sacc[a] = {0,0,0,0};
#pragma unroll
        for (int a = 0; a < 4; ++a) {
            const int row = a*16 + ln16;
#pragma unroll
            for (int kc = 0; kc < 4; ++kc) {
                short8 kf = *reinterpret_cast<const short8*>(&K_lds[((kc*4 + g)*64 + row) * 8]);
                sacc[a] = mfma16(kf, qreg[kc], sacc[a]);
            }
        }

        // ---- online softmax (lane owns q = ln16)
        float p[4][4];
        float tmax = -3e38f;
#pragma unroll
        for (int a = 0; a < 4; ++a)
#pragma unroll
            for (int r = 0; r < 4; ++r) {
                int t = kt*64 + a*16 + g*4 + r;
                float v = (t <= sq) ? sacc[a][r] * scale : -3e38f;
                p[a][r] = v;
                tmax = fmaxf(tmax, v);
            }
        tmax = fmaxf(tmax, __shfl_xor(tmax, 16, 64));
        tmax = fmaxf(tmax, __shfl_xor(tmax, 32, 64));
        float m_new = fmaxf(m_run, tmax);
        float fac = __expf(m_run - m_new);
        float rsum = 0.f;
#pragma unroll
        for (int a = 0; a < 4; ++a)
#pragma unroll
            for (int r = 0; r < 4; ++r) {
                float e = __expf(p[a][r] - m_new);
                p[a][r] = e;
                rsum += e;
            }
        rsum += __shfl_xor(rsum, 16, 64);
        rsum += __shfl_xor(rsum, 32, 64);
        l_run = l_run * fac + rsum;
        m_run = m_new;

        // ---- P -> wave-local LDS (bf16)
        {
            const int ps = (ln16 & 7) << 4;
#pragma unroll
            for (int a = 0; a < 4; ++a) {
                u16x4 quad;
#pragma unroll
                for (int r = 0; r < 4; ++r) quad[r] = f2bf(p[a][r]);
                *reinterpret_cast<u16x4*>(P_my + ((ln16*128 + a*32 + g*8) ^ ps)) = quad;
            }
        }
        // ---- rescale ctx
        float fr[4];
#pragma unroll
        for (int r = 0; r < 4; ++r) fr[r] = __shfl(fac, g*4 + r, 64);
#pragma unroll
        for (int cb = 0; cb < 8; ++cb)
#pragma unroll
            for (int r = 0; r < 4; ++r) acc[cb][r] *= fr[r];

        // ---- PV (swizzled b128 reads)
#pragma unroll
        for (int kc2 = 0; kc2 < 2; ++kc2) {
            short8 pf = *reinterpret_cast<const short8*>(
                P_my + ((ln16*128 + kc2*64 + g*16) ^ ((ln16 & 7) << 4)));
#pragma unroll
            for (int cb = 0; cb < 8; ++cb) {
                const int dv = cb*16 + ln16;
                short8 vf = *reinterpret_cast<const short8*>(
                    V_lds + ((dv*128 + kc2*64 + g*16) ^ ((dv & 7) << 4)));
                acc[cb] = mfma16(pf, vf, acc[cb]);
            }
        }
    }

    // ---- epilogue: normalized partial + LSE
    float inv = 1.0f / l_run;
    float lse = m_run + __logf(l_run);
    float ir[4];
#pragma unroll
    for (int r = 0; r < 4; ++r) ir[r] = __shfl(inv, g*4 + r, 64);
#pragma unroll
    for (int cb = 0; cb < 8; ++cb)
#pragma unroll
        for (int r = 0; r < 4; ++r) {
            int q = qt2*128 + w*16 + g*4 + r;
            opart[((size_t)(c*16 + hh)*S_ + q)*128 + cb*16 + ln16] = f2bf(acc[cb][r] * ir[r]);
        }
    if (g == 0) ml[(size_t)(c*16 + hh)*S_ + qt2*128 + w*16 + ln16] = lse;
}

// ---------------------------------------------------------------------------
// combine: 3-way LSE blend with empty-chunk guard.  grid 2048 x 256.
// ---------------------------------------------------------------------------
__global__ __launch_bounds__(256) void combine(const u16* __restrict__ opart,
                                               const float* __restrict__ ml,
                                               u16* __restrict__ ctx) {
    int t = blockIdx.x * 256 + threadIdx.x;
    int qh = t >> 4;
    int q = qh >> 4, hh = qh & 15;
    int dv0 = (t & 15) * 8;

    float ls[3], m = -3e38f;
#pragma unroll
    for (int c = 0; c < 3; ++c) {
        ls[c] = ml[(size_t)(c*16 + hh) * S_ + q];
        m = fmaxf(m, ls[c]);
    }
    float e[3], s = 0.f;
#pragma unroll
    for (int c = 0; c < 3; ++c) { e[c] = __expf(ls[c] - m); s += e[c]; }
    float is = 1.0f / s;

    float accv[8] = {};
#pragma unroll
    for (int c = 0; c < 3; ++c) {
        if (e[c] > 0.f) {
            u16x8 a = *reinterpret_cast<const u16x8*>(
                &opart[((size_t)(c*16 + hh)*S_ + q)*128 + dv0]);
#pragma unroll
            for (int j = 0; j < 8; ++j) accv[j] += e[c] * bf2f(a[j]);
        }
    }
    u16x8 o;
#pragma unroll
    for (int j = 0; j < 8; ++j) o[j] = f2bf(accv[j] * is);
    *reinterpret_cast<u16x8*>(&ctx[(size_t)q * D_ + hh * DH_ + dv0]) = o;
}

// ---------------------------------------------------------------------------
// r29 orchestration == r28/r26 (proven 366 us); only mgemm gained the
// XCD-chunked block swizzle.
// ws: S0 [0,16Mi): xb_bf -> kmat full-M
//     S1 [16Mi,32Mi): qb_bf full-M -> ctx full-M
//     S2 [32Mi,40Mi): vt (V^T [D][S] per batch) -> wo_bf after flash(b1)
//     S3 [40Mi,44Mi): ckv_bf  S4 [44Mi,46Mi): wuv_bf
// d_out: [0,24Mi) opart; [24Mi,24.4Mi) ml; final out [0,32Mi); ckv tail.
// ---------------------------------------------------------------------------
extern "C" void kernel_launch(void* const* d_in, const int* in_sizes, int n_in,
                              void* d_out, int out_size, void* d_ws, size_t ws_size,
                              hipStream_t stream) {
    const float* x    = (const float*)d_in[0];
    const float* Wq   = (const float*)d_in[1];
    const float* Wdkv = (const float*)d_in[2];
    const float* Wuk  = (const float*)d_in[3];
    const float* Wuv  = (const float*)d_in[4];
    const float* Wo   = (const float*)d_in[5];
    const float* lnw  = (const float*)d_in[6];
    const float* lnb  = (const float*)d_in[7];

    float* out = (float*)d_out;
    float* ckv = out + (size_t)M_ * D_;               // (M,L) real output

    char* ws = (char*)d_ws;
    u16*   xb_bf   = (u16*)(ws);                      // S0 (16 MiB)
    u16*   kmat    = (u16*)(ws);                      //   reuse after xb dead
    u16*   qb_bf   = (u16*)(ws + (size_t)16777216);   // S1 full-M
    u16*   ctx_all = (u16*)(ws + (size_t)16777216);   //   ctx full-M (reuse)
    u16*   vt      = (u16*)(ws + (size_t)33554432);   // S2: V^T per batch
    u16*   wo_bf   = (u16*)(ws + (size_t)33554432);   //   reuse after flash(b1)
    u16*   ckv_bf  = (u16*)(ws + (size_t)41943040);   // S3 full-M (4 MiB)
    u16*   wuv_bf  = (u16*)(ws + (size_t)46137344);   // S4 (2 MiB)

    char*  ob0     = (char*)d_out;
    u16*   wslot   = (u16*)ob0;                       // phase-A weight slot
    float* ckvp    = (float*)(ob0 + 8388608);         // phase-A f32 scratch
    u16*   opart   = (u16*)d_out;                     // [0,24Mi) during flash
    float* ml      = (float*)(ob0 + 25165824);        // [24Mi,24.4Mi)

    dim3 blk(256);

    // ---- Phase A (batch-fused projections) ----
    cvt_bf16<<<dim3(8192), blk, 0, stream>>>(x, xb_bf);
    cvt_bf16<<<dim3(1024), blk, 0, stream>>>(Wdkv, wslot);
    mgemm<float,64,64,2,2,false><<<dim3(L_/64, M_/64), blk, 0, stream>>>(xb_bf, wslot, ckvp, L_, D_, L_);
    ln_fused<<<dim3(M_), blk, 0, stream>>>(ckvp, lnw, lnb, ckv, ckv_bf);
    cvt_bf16<<<dim3(4096), blk, 0, stream>>>(Wq, wslot);
    mgemm<u16,128,128,2,2,false><<<dim3(D_/128, M_/128), blk, 0, stream>>>(xb_bf, wslot, qb_bf, D_, D_, D_);
    cvt_bf16<<<dim3(1024), blk, 0, stream>>>(Wuv, wuv_bf);
    cvt_bf16<<<dim3(1024), blk, 0, stream>>>(Wuk, wslot);
    mgemm<u16,128,128,2,2,false><<<dim3(D_/128, M_/128), blk, 0, stream>>>(ckv_bf, wslot, kmat, D_, L_, D_);

    // ---- Per-batch attention ----
    for (int b = 0; b < B_; ++b) {
        const u16* qb_b    = qb_bf  + (size_t)b * S_ * D_;
        const u16* kmat_b  = kmat   + (size_t)b * S_ * D_;
        const u16* ckvbf_b = ckv_bf + (size_t)b * S_ * L_;
        u16*       ctx_b   = ctx_all + (size_t)b * S_ * D_;

        // v^T_b = (ckv_b @ Wuv^T)^T  -> vt [D][S]
        mgemm<u16,128,64,4,1,true><<<dim3(D_/64, S_/128), blk, 0, stream>>>(ckvbf_b, wuv_bf, vt, D_, L_, S_);

        // 3-way split flash + combine (ctx into dead qb_b half)
        flash_split<<<dim3(16, 16, 3), dim3(512), 0, stream>>>(
            qb_b, kmat_b, vt, opart, ml);
        combine<<<dim3(2048), blk, 0, stream>>>(opart, ml, ctx_b);
    }

    // ---- Merged output projection: out = ctx_all @ Wo^T (M=4096) ----
    cvt_bf16<<<dim3(4096), blk, 0, stream>>>(Wo, wo_bf);
    mgemm<float,128,128,2,2,false><<<dim3(D_/128, M_/128), blk, 0, stream>>>(ctx_all, wo_bf, out, D_, D_, D_);
}